// Round 3
// baseline (510.229 us; speedup 1.0000x reference)
//
#include <hip/hip_runtime.h>
#include <hip/hip_bf16.h>
#include <stdint.h>

typedef unsigned short u16;
typedef __bf16 bf16x8 __attribute__((ext_vector_type(8)));
typedef float f32x4 __attribute__((ext_vector_type(4)));

__device__ __forceinline__ u16 f2bf(float f) {
  union { float f; uint32_t u; } v; v.f = f;
  uint32_t u = v.u;
  return (u16)((u + 0x7FFFu + ((u >> 16) & 1u)) >> 16);
}

__device__ __forceinline__ f32x4 mfma16(bf16x8 a, bf16x8 b, f32x4 c) {
  return __builtin_amdgcn_mfma_f32_16x16x32_bf16(a, b, c, 0, 0, 0);
}

#define GLOBAL_TO_LDS16(g, l)                                                  \
  __builtin_amdgcn_global_load_lds(                                            \
      (const __attribute__((address_space(1))) void*)(g),                      \
      (__attribute__((address_space(3))) void*)(l), 16, 0, 0)

// counted-vmcnt barrier (T4): steady-state wait leaves one full tile's loads
// in flight across the barrier (never drains to 0 in the main loop).
// lgkmcnt(0) is included defensively: all ds_reads are provably complete here
// anyway (MFMA consumption precedes this point), so it costs ~0 but makes the
// slot-overwrite hazard impossible by construction.
template <int N>
__device__ __forceinline__ void vm_wait_barrier() {
  if constexpr (N == 0)      asm volatile("s_waitcnt vmcnt(0) lgkmcnt(0)" ::: "memory");
  else if constexpr (N == 3) asm volatile("s_waitcnt vmcnt(3) lgkmcnt(0)" ::: "memory");
  else                       asm volatile("s_waitcnt vmcnt(4) lgkmcnt(0)" ::: "memory");
  __builtin_amdgcn_s_barrier();
  asm volatile("" ::: "memory");
}

// ---------------- fused f32 -> bf16 conversion (x | qkv_w | proj_w) --------
__global__ void cvt_bf16_all(const float* __restrict__ x, u16* __restrict__ xb,
                             const float* __restrict__ qw, u16* __restrict__ qwb,
                             const float* __restrict__ pw, u16* __restrict__ pwb) {
  int blk = blockIdx.x;
  const float* src; u16* dst; int i;
  if (blk < 24576)        { src = x;  dst = xb;  i = blk * 256 + threadIdx.x; }
  else if (blk < 26304)   { src = qw; dst = qwb; i = (blk - 24576) * 256 + threadIdx.x; }
  else                    { src = pw; dst = pwb; i = (blk - 26304) * 256 + threadIdx.x; }
  float4 f = ((const float4*)src)[i];
  ushort4 o;
  o.x = f2bf(f.x); o.y = f2bf(f.y); o.z = f2bf(f.z); o.w = f2bf(f.w);
  ((ushort4*)dst)[i] = o;
}

// ---------------- pipelined GEMM: 3-slot LDS ring, counted vmcnt ----------
// MODE 0: qk   (BM=256, BN=256, swapped mfma, bf16 q/k scatter + q scale)
// MODE 1: v    (BM=256, BN=128, normal mfma, vT scatter)
// MODE 2: proj (BM=256, BN=128, swapped mfma, f32 out + bias)
// BK=32, KT=24. Stage tile t+2 while computing tile t; steady-state wait is
// vmcnt(LPT): retires exactly tile t+1's loads, leaves tile t+2's in flight
// across the barrier (outstanding = 2*LPT at the wait point).
// Slot being staged (t+2)%3 was last computed at iter t-1; every wave's
// ds_reads from it completed (lgkmcnt(0) before that iter's MFMAs, which
// precede the barrier) -> no RAW race.
// LDS rows are 32 bf16 (64B): chunk swizzle c ^ (r&3) ^ ((r>>2)&3) gives
// <=2-way bank aliasing on ds_read_b128 (free, m136), applied on the global
// SOURCE address (linear global_load_lds dest, rule #21).
template <int MODE>
__global__ __launch_bounds__(512, (MODE == 0) ? 2 : 4) void gemm_pipe(
    const u16* __restrict__ A, const u16* __restrict__ Bt, int nbase,
    u16* __restrict__ o_q, u16* __restrict__ o_k, u16* __restrict__ o_vT,
    const float* __restrict__ bias, float* __restrict__ o_f32) {
  constexpr int BN  = (MODE == 0) ? 256 : 128;
  constexpr int WN  = (MODE == 0) ? 4 : 2;      // waves along N
  constexpr int MF  = (MODE == 0) ? 8 : 4;      // 16-row frags per wave
  constexpr int NBS = (MODE == 0) ? 2 : 1;      // B stage instrs / thread
  constexpr int LPT = 2 + NBS;                  // loads per tile per thread
  constexpr int KT  = 24;                       // 768 / 32
  const int K = 768;

  __shared__ u16 As[3 * 256 * 32];
  __shared__ u16 Bs[3 * BN * 32];

  int tid = threadIdx.x;
  int wid = tid >> 6, lane = tid & 63;
  int quad = lane >> 4, lrow = lane & 15;
  int wm = wid / WN, wn = wid % WN;
  int m0 = blockIdx.y * 256;
  int n0l = blockIdx.x * BN;          // local n (within this kernel's range)
  int n0g = nbase + n0l;              // row offset into Bt

  // stage source/dest precompute (pre-swizzled global source, linear LDS dst)
  const u16* aSrc[2]; int aDst[2];
#pragma unroll
  for (int s = 0; s < 2; s++) {
    int p = (wid + s * 8) * 64 + lane;          // chunk id in [0, 1024)
    int r = p >> 2;
    int c = (p & 3) ^ (r & 3) ^ ((r >> 2) & 3);
    aSrc[s] = A + (size_t)(m0 + r) * K + c * 8;
    aDst[s] = p * 8;
  }
  const u16* bSrc[NBS]; int bDst[NBS];
#pragma unroll
  for (int s = 0; s < NBS; s++) {
    int p = (wid + s * 8) * 64 + lane;          // [0, BN*4)
    int r = p >> 2;
    int c = (p & 3) ^ (r & 3) ^ ((r >> 2) & 3);
    bSrc[s] = Bt + (size_t)(n0g + r) * K + c * 8;
    bDst[s] = p * 8;
  }

  f32x4 acc[MF][4] = {};

  auto STAGE = [&](int koff, int slot) {
#pragma unroll
    for (int s = 0; s < 2; s++)
      GLOBAL_TO_LDS16(aSrc[s] + koff, As + slot * 8192 + aDst[s]);
#pragma unroll
    for (int s = 0; s < NBS; s++)
      GLOBAL_TO_LDS16(bSrc[s] + koff, Bs + slot * (BN * 32) + bDst[s]);
  };

  auto COMPUTE = [&](int slot) {
    const u16* Ab = As + slot * 8192;
    const u16* Bb = Bs + slot * (BN * 32);
    bf16x8 af[MF], bfr[4];
#pragma unroll
    for (int m = 0; m < MF; m++) {
      int r = wm * (MF * 16) + m * 16 + lrow;
      af[m] = *(const bf16x8*)(Ab + r * 32 + ((quad ^ (r & 3) ^ ((r >> 2) & 3)) << 3));
    }
#pragma unroll
    for (int n = 0; n < 4; n++) {
      int r = wn * 64 + n * 16 + lrow;
      bfr[n] = *(const bf16x8*)(Bb + r * 32 + ((quad ^ (r & 3) ^ ((r >> 2) & 3)) << 3));
    }
    __builtin_amdgcn_s_setprio(1);
#pragma unroll
    for (int m = 0; m < MF; m++)
#pragma unroll
      for (int n = 0; n < 4; n++)
        acc[m][n] = (MODE != 1) ? mfma16(bfr[n], af[m], acc[m][n])
                                : mfma16(af[m], bfr[n], acc[m][n]);
    __builtin_amdgcn_s_setprio(0);
  };

  // prologue: tiles 0,1 in flight; retire tile 0, keep tile 1 in flight
  STAGE(0, 0);
  STAGE(32, 1);
  vm_wait_barrier<LPT>();

  int cs = 0, ns = 2, koff = 64;
  for (int t = 0; t < KT - 2; ++t) {
    STAGE(koff, ns);              // tile t+2 -> slot (t+2)%3
    COMPUTE(cs);                  // tile t
    vm_wait_barrier<LPT>();       // retires tile t+1, leaves t+2 in flight
    koff += 32;
    cs = (cs == 2) ? 0 : cs + 1;
    ns = (ns == 2) ? 0 : ns + 1;
  }
  COMPUTE((KT - 2) % 3);          // tile 22
  vm_wait_barrier<0>();           // drain tile 23
  COMPUTE((KT - 1) % 3);          // tile 23

  // ---------------- epilogues ----------------
  if constexpr (MODE == 0) {
    // swapped: frag rows (quad*4+reg) = feature, cols (lrow) = seq
#pragma unroll
    for (int n = 0; n < 4; n++) {
      int nf = n0l + wn * 64 + n * 16 + quad * 4;   // 0..1535
      int t = nf >= 768;
      int f = nf - (t ? 768 : 0);
      u16* dst = t ? o_k : o_q;
      float sc = t ? 1.0f : 0.125f;
      int h = f >> 6, d0 = f & 63;
#pragma unroll
      for (int m = 0; m < MF; m++) {
        int seqg = m0 + wm * 128 + m * 16 + lrow;
        int b = seqg >> 7, s = seqg & 127;
        ushort4 o;
        o.x = f2bf(acc[m][n][0] * sc); o.y = f2bf(acc[m][n][1] * sc);
        o.z = f2bf(acc[m][n][2] * sc); o.w = f2bf(acc[m][n][3] * sc);
        *(ushort4*)(dst + ((size_t)(b * 12 + h)) * 8192 + s * 64 + d0) = o;
      }
    }
  } else if constexpr (MODE == 1) {
    // normal: frag rows (quad*4+reg) = seq, cols (lrow) = feature
#pragma unroll
    for (int n = 0; n < 4; n++) {
      int f = n0l + wn * 64 + n * 16 + lrow;        // 0..767 (v features)
      int h = f >> 6, d = f & 63;
#pragma unroll
      for (int m = 0; m < MF; m++) {
        int seq0 = m0 + wm * 64 + m * 16 + quad * 4;
        int b = seq0 >> 7, s0 = seq0 & 127;
        ushort4 o;
        o.x = f2bf(acc[m][n][0]); o.y = f2bf(acc[m][n][1]);
        o.z = f2bf(acc[m][n][2]); o.w = f2bf(acc[m][n][3]);
        *(ushort4*)(o_vT + ((size_t)(b * 12 + h)) * 8192 + d * 128 + s0) = o;
      }
    }
  } else {
    // swapped, f32 + bias
#pragma unroll
    for (int n = 0; n < 4; n++) {
      int nf = n0l + wn * 64 + n * 16 + quad * 4;
      float4 b4 = *(const float4*)(bias + nf);
#pragma unroll
      for (int m = 0; m < MF; m++) {
        int mr = m0 + wm * 64 + m * 16 + lrow;
        float4 o;
        o.x = acc[m][n][0] + b4.x; o.y = acc[m][n][1] + b4.y;
        o.z = acc[m][n][2] + b4.z; o.w = acc[m][n][3] + b4.w;
        *(float4*)(o_f32 + (size_t)mr * 768 + nf) = o;
      }
    }
  }
}

// ---------------- attention: one block per (b,h), 512 threads -------------
// (unchanged from the verified baseline)
__global__ __launch_bounds__(512) void attn_kernel(
    const u16* __restrict__ q, const u16* __restrict__ k, const u16* __restrict__ vT,
    const float* __restrict__ mask, const float* __restrict__ bias_table,
    u16* __restrict__ attn_out) {
  __shared__ u16 smem[2 * 128 * 64];  // qs | ks, then P[128][128]
  __shared__ u16 vTs[64 * 128];
  __shared__ float bias_s[255];
  u16* qs = smem;
  u16* ks = smem + 128 * 64;
  u16* ps = smem;
  int tid = threadIdx.x;
  int wave = tid >> 6, lane = tid & 63;
  int quad = lane >> 4, lrow = lane & 15;
  int bh = blockIdx.x;
  int b = bh / 12, h = bh - b * 12;
  int w = b & 63;
  if (tid < 255) bias_s[tid] = bias_table[tid * 12 + h];
  const u16* qg = q + (size_t)bh * 8192;
  const u16* kg = k + (size_t)bh * 8192;
  const u16* vg = vT + (size_t)bh * 8192;
#pragma unroll
  for (int s = 0; s < 2; s++) {
    int p = s * 512 + tid;
    int row = p >> 3, c = (p & 7) ^ (row & 7);
    GLOBAL_TO_LDS16(qg + row * 64 + c * 8, qs + p * 8);
    GLOBAL_TO_LDS16(kg + row * 64 + c * 8, ks + p * 8);
    int dd = p >> 4, cv = (p & 15) ^ (dd & 7);
    GLOBAL_TO_LDS16(vg + dd * 128 + cv * 8, vTs + p * 8);
  }
  __syncthreads();

  int row = wave * 16 + lrow;
  f32x4 sacc[8] = {};
#pragma unroll
  for (int kk = 0; kk < 2; kk++) {
    bf16x8 qf = *(const bf16x8*)(qs + row * 64 + ((((kk << 2) | quad) ^ (row & 7)) << 3));
#pragma unroll
    for (int i = 0; i < 8; i++) {
      int rk = i * 16 + lrow;
      bf16x8 kf = *(const bf16x8*)(ks + rk * 64 + ((((kk << 2) | quad) ^ (rk & 7)) << 3));
      sacc[i] = mfma16(kf, qf, sacc[i]);
    }
  }
  const float* mrow = mask + (size_t)w * 16384 + row * 128;
#pragma unroll
  for (int i = 0; i < 8; i++) {
    int c0 = i * 16 + quad * 4;
    float4 m4 = *(const float4*)(mrow + c0);
    sacc[i][0] += bias_s[row - (c0 + 0) + 127] + m4.x;
    sacc[i][1] += bias_s[row - (c0 + 1) + 127] + m4.y;
    sacc[i][2] += bias_s[row - (c0 + 2) + 127] + m4.z;
    sacc[i][3] += bias_s[row - (c0 + 3) + 127] + m4.w;
  }
  float mx = sacc[0][0];
#pragma unroll
  for (int i = 0; i < 8; i++)
#pragma unroll
    for (int r = 0; r < 4; r++) mx = fmaxf(mx, sacc[i][r]);
  mx = fmaxf(mx, __shfl_xor(mx, 16, 64));
  mx = fmaxf(mx, __shfl_xor(mx, 32, 64));
  float sum = 0.f;
#pragma unroll
  for (int i = 0; i < 8; i++)
#pragma unroll
    for (int r = 0; r < 4; r++) {
      float e = __expf(sacc[i][r] - mx);
      sacc[i][r] = e;
      sum += e;
    }
  sum += __shfl_xor(sum, 16, 64);
  sum += __shfl_xor(sum, 32, 64);
  float inv = 1.f / sum;
  __syncthreads();
#pragma unroll
  for (int i = 0; i < 8; i++) {
    int chunk = i * 2 + (quad >> 1);
    int pos = chunk ^ (row & 7);
    ushort4 o;
    o.x = f2bf(sacc[i][0] * inv); o.y = f2bf(sacc[i][1] * inv);
    o.z = f2bf(sacc[i][2] * inv); o.w = f2bf(sacc[i][3] * inv);
    *(ushort4*)(ps + row * 128 + pos * 8 + (quad & 1) * 4) = o;
  }
  __syncthreads();

  f32x4 oacc[4] = {};
#pragma unroll
  for (int kk = 0; kk < 4; kk++) {
    bf16x8 pf = *(const bf16x8*)(ps + row * 128 + ((((kk << 2) | quad) ^ (row & 7)) << 3));
#pragma unroll
    for (int jd = 0; jd < 4; jd++) {
      int rd = jd * 16 + lrow;
      bf16x8 vf = *(const bf16x8*)(vTs + rd * 128 + ((((kk << 2) | quad) ^ (rd & 7)) << 3));
      oacc[jd] = mfma16(vf, pf, oacc[jd]);
    }
  }
#pragma unroll
  for (int jd = 0; jd < 4; jd++) {
    int d0 = jd * 16 + quad * 4;
    int seq = wave * 16 + lrow;
    ushort4 o;
    o.x = f2bf(oacc[jd][0]); o.y = f2bf(oacc[jd][1]);
    o.z = f2bf(oacc[jd][2]); o.w = f2bf(oacc[jd][3]);
    *(ushort4*)(attn_out + ((size_t)(b * 128 + seq)) * 768 + h * 64 + d0) = o;
  }
}

extern "C" void kernel_launch(void* const* d_in, const int* in_sizes, int n_in,
                              void* d_out, int out_size, void* d_ws, size_t ws_size,
                              hipStream_t stream) {
  const float* x          = (const float*)d_in[0];
  const float* mask       = (const float*)d_in[1];
  const float* qkv_w      = (const float*)d_in[2];
  const float* bias_table = (const float*)d_in[3];
  const float* proj_w     = (const float*)d_in[4];
  const float* proj_b     = (const float*)d_in[5];
  float* out = (float*)d_out;
  char* ws = (char*)d_ws;
  u16* q_b    = (u16*)(ws);                    // 50331648
  u16* k_b    = (u16*)(ws + 50331648);         // 50331648
  u16* vT_b   = (u16*)(ws + 100663296);        // 50331648
  u16* x_b    = (u16*)(ws + 150994944);        // 50331648 (x bf16, reused as attn_out)
  u16* qw_b   = (u16*)(ws + 201326592);        // 3538944
  u16* pw_b   = (u16*)(ws + 204865536);        // 1179648
  u16* attn_b = x_b;

  cvt_bf16_all<<<26880, 256, 0, stream>>>(x, x_b, qkv_w, qw_b, proj_w, pw_b);
  gemm_pipe<0><<<dim3(6, 128), 512, 0, stream>>>(x_b, qw_b, 0,
                                                 q_b, k_b, vT_b, nullptr, nullptr);
  gemm_pipe<1><<<dim3(6, 128), 512, 0, stream>>>(x_b, qw_b, 1536,
                                                 q_b, k_b, vT_b, nullptr, nullptr);
  attn_kernel<<<3072, 512, 0, stream>>>(q_b, k_b, vT_b, mask, bias_table, attn_b);
  gemm_pipe<2><<<dim3(6, 128), 512, 0, stream>>>(attn_b, pw_b, 0,
                                                 nullptr, nullptr, nullptr, proj_b, out);
}

// Round 4
// 444.179 us; speedup vs baseline: 1.1487x; 1.1487x over previous
//
#include <hip/hip_runtime.h>
#include <hip/hip_bf16.h>
#include <stdint.h>

typedef unsigned short u16;
typedef __bf16 bf16x8 __attribute__((ext_vector_type(8)));
typedef float f32x4 __attribute__((ext_vector_type(4)));

__device__ __forceinline__ u16 f2bf(float f) {
  union { float f; uint32_t u; } v; v.f = f;
  uint32_t u = v.u;
  return (u16)((u + 0x7FFFu + ((u >> 16) & 1u)) >> 16);
}

__device__ __forceinline__ f32x4 mfma16(bf16x8 a, bf16x8 b, f32x4 c) {
  return __builtin_amdgcn_mfma_f32_16x16x32_bf16(a, b, c, 0, 0, 0);
}

#define GLOBAL_TO_LDS16(g, l)                                                  \
  __builtin_amdgcn_global_load_lds(                                            \
      (const __attribute__((address_space(1))) void*)(g),                      \
      (__attribute__((address_space(3))) void*)(l), 16, 0, 0)

// T1: XCD-aware block swizzle. Default dispatch round-robins consecutive
// workgroup ids across the 8 XCDs; remap so each XCD owns a CONTIGUOUS chunk
// of logical blocks -> blocks sharing an A-panel / mask window land on the
// same private L2. Bijective iff nwg % 8 == 0 (true for all grids here).
__device__ __forceinline__ int xcd_swz(int lin, int nwg) {
  return (lin & 7) * (nwg >> 3) + (lin >> 3);
}

// ---------------- fused f32 -> bf16 conversion (x | qkv_w | proj_w) --------
__global__ void cvt_bf16_all(const float* __restrict__ x, u16* __restrict__ xb,
                             const float* __restrict__ qw, u16* __restrict__ qwb,
                             const float* __restrict__ pw, u16* __restrict__ pwb) {
  int blk = blockIdx.x;
  const float* src; u16* dst; int i;
  if (blk < 24576)        { src = x;  dst = xb;  i = blk * 256 + threadIdx.x; }
  else if (blk < 26304)   { src = qw; dst = qwb; i = (blk - 24576) * 256 + threadIdx.x; }
  else                    { src = pw; dst = pwb; i = (blk - 26304) * 256 + threadIdx.x; }
  float4 f = ((const float4*)src)[i];
  ushort4 o;
  o.x = f2bf(f.x); o.y = f2bf(f.y); o.z = f2bf(f.z); o.w = f2bf(f.w);
  ((ushort4*)dst)[i] = o;
}

// ---------------- QKV GEMM (481us-verified structure + XCD swizzle) -------
template <bool SWAP>
__global__ __launch_bounds__(256) void qkv_gemm(
    const u16* __restrict__ A, const u16* __restrict__ Bt, int nbase,
    u16* __restrict__ q, u16* __restrict__ k, u16* __restrict__ vT) {
  const int K = 768;
  __shared__ u16 As[128 * 64];
  __shared__ u16 Bs[128 * 64];
  int tid = threadIdx.x;
  int wave = tid >> 6, lane = tid & 63;
  int quad = lane >> 4, lrow = lane & 15;
  int lin = blockIdx.x + gridDim.x * blockIdx.y;
  int swz = xcd_swz(lin, gridDim.x * gridDim.y);
  int bx = swz % gridDim.x, by = swz / gridDim.x;
  int m0 = by * 128, n0 = nbase + bx * 128;
  int wr = (wave >> 1) * 64, wc = (wave & 1) * 64;

  const u16* asrc[4]; const u16* bsrc[4]; int ldst[4];
#pragma unroll
  for (int s = 0; s < 4; s++) {
    int p = (wave * 4 + s) * 64 + lane;
    int row = p >> 3, cp = p & 7;
    int c = cp ^ (row & 7);
    asrc[s] = A + (size_t)(m0 + row) * K + c * 8;
    bsrc[s] = Bt + (size_t)(n0 + row) * K + c * 8;
    ldst[s] = p * 8;
  }
  f32x4 acc[4][4] = {};
  for (int k0 = 0; k0 < K; k0 += 64) {
#pragma unroll
    for (int s = 0; s < 4; s++) {
      GLOBAL_TO_LDS16(asrc[s] + k0, As + ldst[s]);
      GLOBAL_TO_LDS16(bsrc[s] + k0, Bs + ldst[s]);
    }
    __syncthreads();
#pragma unroll
    for (int kk = 0; kk < 2; kk++) {
      bf16x8 am[4], bn[4];
#pragma unroll
      for (int i = 0; i < 4; i++) {
        int r = wr + i * 16 + lrow;
        am[i] = *(const bf16x8*)(As + r * 64 + ((((kk << 2) | quad) ^ (r & 7)) << 3));
      }
#pragma unroll
      for (int j = 0; j < 4; j++) {
        int r = wc + j * 16 + lrow;
        bn[j] = *(const bf16x8*)(Bs + r * 64 + ((((kk << 2) | quad) ^ (r & 7)) << 3));
      }
#pragma unroll
      for (int i = 0; i < 4; i++)
#pragma unroll
        for (int j = 0; j < 4; j++)
          acc[i][j] = SWAP ? mfma16(bn[i], am[j], acc[i][j])
                           : mfma16(am[i], bn[j], acc[i][j]);
    }
    __syncthreads();
  }
  int b = m0 >> 7;
  if (SWAP) {
    int t = n0 / 768;
    float s = (t == 0) ? 0.125f : 1.0f;
    u16* dst = (t == 0) ? q : k;
#pragma unroll
    for (int i = 0; i < 4; i++) {
      int nb = (n0 - t * 768) + wc + i * 16 + quad * 4;
      int h = nb >> 6, d0 = nb & 63;
#pragma unroll
      for (int j = 0; j < 4; j++) {
        int seq = wr + j * 16 + lrow;
        ushort4 o;
        o.x = f2bf(acc[i][j][0] * s); o.y = f2bf(acc[i][j][1] * s);
        o.z = f2bf(acc[i][j][2] * s); o.w = f2bf(acc[i][j][3] * s);
        *(ushort4*)(dst + ((size_t)(b * 12 + h)) * 8192 + seq * 64 + d0) = o;
      }
    }
  } else {
#pragma unroll
    for (int j = 0; j < 4; j++) {
      int nb = (n0 - 1536) + wc + j * 16 + lrow;
      int h = nb >> 6, d = nb & 63;
#pragma unroll
      for (int i = 0; i < 4; i++) {
        int seq0 = wr + i * 16 + quad * 4;
        ushort4 o;
        o.x = f2bf(acc[i][j][0]); o.y = f2bf(acc[i][j][1]);
        o.z = f2bf(acc[i][j][2]); o.w = f2bf(acc[i][j][3]);
        *(ushort4*)(vT + ((size_t)(b * 12 + h)) * 8192 + d * 128 + seq0) = o;
      }
    }
  }
}

// ---------------- attention: one block per (b,h), 512 threads -------------
// (481us-verified structure + XCD swizzle: consecutive bh share the mask
//  window (b&63) -> same-XCD L2 reuse of the 64KB mask slab)
__global__ __launch_bounds__(512) void attn_kernel(
    const u16* __restrict__ q, const u16* __restrict__ k, const u16* __restrict__ vT,
    const float* __restrict__ mask, const float* __restrict__ bias_table,
    u16* __restrict__ attn_out) {
  __shared__ u16 smem[2 * 128 * 64];  // qs | ks, then P[128][128]
  __shared__ u16 vTs[64 * 128];
  __shared__ float bias_s[255];
  u16* qs = smem;
  u16* ks = smem + 128 * 64;
  u16* ps = smem;
  int tid = threadIdx.x;
  int wave = tid >> 6, lane = tid & 63;
  int quad = lane >> 4, lrow = lane & 15;
  int bh = xcd_swz(blockIdx.x, gridDim.x);
  int b = bh / 12, h = bh - b * 12;
  int w = b & 63;
  if (tid < 255) bias_s[tid] = bias_table[tid * 12 + h];
  const u16* qg = q + (size_t)bh * 8192;
  const u16* kg = k + (size_t)bh * 8192;
  const u16* vg = vT + (size_t)bh * 8192;
#pragma unroll
  for (int s = 0; s < 2; s++) {
    int p = s * 512 + tid;
    int row = p >> 3, c = (p & 7) ^ (row & 7);
    GLOBAL_TO_LDS16(qg + row * 64 + c * 8, qs + p * 8);
    GLOBAL_TO_LDS16(kg + row * 64 + c * 8, ks + p * 8);
    int dd = p >> 4, cv = (p & 15) ^ (dd & 7);
    GLOBAL_TO_LDS16(vg + dd * 128 + cv * 8, vTs + p * 8);
  }
  __syncthreads();

  int row = wave * 16 + lrow;
  f32x4 sacc[8] = {};
#pragma unroll
  for (int kk = 0; kk < 2; kk++) {
    bf16x8 qf = *(const bf16x8*)(qs + row * 64 + ((((kk << 2) | quad) ^ (row & 7)) << 3));
#pragma unroll
    for (int i = 0; i < 8; i++) {
      int rk = i * 16 + lrow;
      bf16x8 kf = *(const bf16x8*)(ks + rk * 64 + ((((kk << 2) | quad) ^ (rk & 7)) << 3));
      sacc[i] = mfma16(kf, qf, sacc[i]);
    }
  }
  const float* mrow = mask + (size_t)w * 16384 + row * 128;
#pragma unroll
  for (int i = 0; i < 8; i++) {
    int c0 = i * 16 + quad * 4;
    float4 m4 = *(const float4*)(mrow + c0);
    sacc[i][0] += bias_s[row - (c0 + 0) + 127] + m4.x;
    sacc[i][1] += bias_s[row - (c0 + 1) + 127] + m4.y;
    sacc[i][2] += bias_s[row - (c0 + 2) + 127] + m4.z;
    sacc[i][3] += bias_s[row - (c0 + 3) + 127] + m4.w;
  }
  float mx = sacc[0][0];
#pragma unroll
  for (int i = 0; i < 8; i++)
#pragma unroll
    for (int r = 0; r < 4; r++) mx = fmaxf(mx, sacc[i][r]);
  mx = fmaxf(mx, __shfl_xor(mx, 16, 64));
  mx = fmaxf(mx, __shfl_xor(mx, 32, 64));
  float sum = 0.f;
#pragma unroll
  for (int i = 0; i < 8; i++)
#pragma unroll
    for (int r = 0; r < 4; r++) {
      float e = __expf(sacc[i][r] - mx);
      sacc[i][r] = e;
      sum += e;
    }
  sum += __shfl_xor(sum, 16, 64);
  sum += __shfl_xor(sum, 32, 64);
  float inv = 1.f / sum;
  __syncthreads();
#pragma unroll
  for (int i = 0; i < 8; i++) {
    int chunk = i * 2 + (quad >> 1);
    int pos = chunk ^ (row & 7);
    ushort4 o;
    o.x = f2bf(sacc[i][0] * inv); o.y = f2bf(sacc[i][1] * inv);
    o.z = f2bf(sacc[i][2] * inv); o.w = f2bf(sacc[i][3] * inv);
    *(ushort4*)(ps + row * 128 + pos * 8 + (quad & 1) * 4) = o;
  }
  __syncthreads();

  f32x4 oacc[4] = {};
#pragma unroll
  for (int kk = 0; kk < 4; kk++) {
    bf16x8 pf = *(const bf16x8*)(ps + row * 128 + ((((kk << 2) | quad) ^ (row & 7)) << 3));
#pragma unroll
    for (int jd = 0; jd < 4; jd++) {
      int rd = jd * 16 + lrow;
      bf16x8 vf = *(const bf16x8*)(vTs + rd * 128 + ((((kk << 2) | quad) ^ (rd & 7)) << 3));
      oacc[jd] = mfma16(vf, pf, oacc[jd]);
    }
  }
#pragma unroll
  for (int jd = 0; jd < 4; jd++) {
    int d0 = jd * 16 + quad * 4;
    int seq = wave * 16 + lrow;
    ushort4 o;
    o.x = f2bf(oacc[jd][0]); o.y = f2bf(oacc[jd][1]);
    o.z = f2bf(oacc[jd][2]); o.w = f2bf(oacc[jd][3]);
    *(ushort4*)(attn_out + ((size_t)(b * 128 + seq)) * 768 + h * 64 + d0) = o;
  }
}

// ---------------- proj GEMM (481us-verified structure + XCD swizzle) ------
__global__ __launch_bounds__(256) void proj_gemm(
    const u16* __restrict__ A, const u16* __restrict__ Bt,
    const float* __restrict__ bias, float* __restrict__ out) {
  const int K = 768;
  __shared__ u16 As[128 * 64];
  __shared__ u16 Bs[128 * 64];
  int tid = threadIdx.x;
  int wave = tid >> 6, lane = tid & 63;
  int quad = lane >> 4, lrow = lane & 15;
  int lin = blockIdx.x + gridDim.x * blockIdx.y;
  int swz = xcd_swz(lin, gridDim.x * gridDim.y);
  int bx = swz % gridDim.x, by = swz / gridDim.x;
  int m0 = by * 128, n0 = bx * 128;
  int wr = (wave >> 1) * 64, wc = (wave & 1) * 64;

  const u16* asrc[4]; const u16* bsrc[4]; int ldst[4];
#pragma unroll
  for (int s = 0; s < 4; s++) {
    int p = (wave * 4 + s) * 64 + lane;
    int row = p >> 3, c = (p & 7) ^ (row & 7);
    asrc[s] = A + (size_t)(m0 + row) * K + c * 8;
    bsrc[s] = Bt + (size_t)(n0 + row) * K + c * 8;
    ldst[s] = p * 8;
  }
  f32x4 acc[4][4] = {};
  for (int k0 = 0; k0 < K; k0 += 64) {
#pragma unroll
    for (int s = 0; s < 4; s++) {
      GLOBAL_TO_LDS16(asrc[s] + k0, As + ldst[s]);
      GLOBAL_TO_LDS16(bsrc[s] + k0, Bs + ldst[s]);
    }
    __syncthreads();
#pragma unroll
    for (int kk = 0; kk < 2; kk++) {
      bf16x8 am[4], bn[4];
#pragma unroll
      for (int i = 0; i < 4; i++) {
        int r = wr + i * 16 + lrow;
        am[i] = *(const bf16x8*)(As + r * 64 + ((((kk << 2) | quad) ^ (r & 7)) << 3));
      }
#pragma unroll
      for (int j = 0; j < 4; j++) {
        int r = wc + j * 16 + lrow;
        bn[j] = *(const bf16x8*)(Bs + r * 64 + ((((kk << 2) | quad) ^ (r & 7)) << 3));
      }
#pragma unroll
      for (int i = 0; i < 4; i++)
#pragma unroll
        for (int j = 0; j < 4; j++)
          acc[i][j] = mfma16(bn[i], am[j], acc[i][j]);
    }
    __syncthreads();
  }
#pragma unroll
  for (int i = 0; i < 4; i++) {
    int nb = n0 + wc + i * 16 + quad * 4;
    float4 b4 = *(const float4*)(bias + nb);
#pragma unroll
    for (int j = 0; j < 4; j++) {
      int m = m0 + wr + j * 16 + lrow;
      float4 o;
      o.x = acc[i][j][0] + b4.x; o.y = acc[i][j][1] + b4.y;
      o.z = acc[i][j][2] + b4.z; o.w = acc[i][j][3] + b4.w;
      *(float4*)(out + (size_t)m * 768 + nb) = o;
    }
  }
}

extern "C" void kernel_launch(void* const* d_in, const int* in_sizes, int n_in,
                              void* d_out, int out_size, void* d_ws, size_t ws_size,
                              hipStream_t stream) {
  const float* x          = (const float*)d_in[0];
  const float* mask       = (const float*)d_in[1];
  const float* qkv_w      = (const float*)d_in[2];
  const float* bias_table = (const float*)d_in[3];
  const float* proj_w     = (const float*)d_in[4];
  const float* proj_b     = (const float*)d_in[5];
  float* out = (float*)d_out;
  char* ws = (char*)d_ws;
  u16* q_b    = (u16*)(ws);                    // 50331648
  u16* k_b    = (u16*)(ws + 50331648);         // 50331648
  u16* vT_b   = (u16*)(ws + 100663296);        // 50331648
  u16* x_b    = (u16*)(ws + 150994944);        // 50331648 (x bf16, reused as attn_out)
  u16* qw_b   = (u16*)(ws + 201326592);        // 3538944
  u16* pw_b   = (u16*)(ws + 204865536);        // 1179648
  u16* attn_b = x_b;

  cvt_bf16_all<<<26880, 256, 0, stream>>>(x, x_b, qkv_w, qw_b, proj_w, pw_b);
  qkv_gemm<true><<<dim3(12, 256), 256, 0, stream>>>(x_b, qw_b, 0, q_b, k_b, vT_b);
  qkv_gemm<false><<<dim3(6, 256), 256, 0, stream>>>(x_b, qw_b, 1536, q_b, k_b, vT_b);
  attn_kernel<<<3072, 512, 0, stream>>>(q_b, k_b, vT_b, mask, bias_table, attn_b);
  proj_gemm<<<dim3(6, 256), 256, 0, stream>>>(attn_b, pw_b, proj_b, out);
}